// Round 4
// baseline (1465.436 us; speedup 1.0000x reference)
//
#include <hip/hip_runtime.h>
#include <math.h>

#define IN_F 512
#define NH   64
#define NC   32
#define PPR_ALPHA 0.1f
#define NITER 10
#define BROWS 64            // rows per bucket
#define COLBITS 17          // col fits 17 bits (N = 100000 < 131072)
#define MAXBK 2048          // max buckets supported (N <= 131072)

// ---------------- MLP kernel 1: h = tanh(x @ w1.T), h is [N][64] ----------------
__global__ __launch_bounds__(256) void k_mlp1(const float* __restrict__ x,
                                              const float* __restrict__ w1,
                                              float* __restrict__ h, int N) {
    __shared__ float xsf[32 * 132];
    __shared__ float wsf[32 * 68];

    const int tid = threadIdx.x;
    const int n0  = blockIdx.x * 128;
    const int hq  = tid & 15;
    const int nq  = tid >> 4;

    float acc[8][4];
#pragma unroll
    for (int j = 0; j < 8; ++j)
#pragma unroll
        for (int i = 0; i < 4; ++i) acc[j][i] = 0.f;

    for (int kt = 0; kt < IN_F / 32; ++kt) {
        const int k0 = kt * 32;
        __syncthreads();
        {
            const int f4 = tid & 7;
            const int r0 = tid >> 3;
#pragma unroll
            for (int q2 = 0; q2 < 4; ++q2) {
                const int r = r0 + 32 * q2;
                int row = n0 + r; if (row >= N) row = N - 1;
                const float4 v = *(const float4*)(x + (size_t)row * IN_F + k0 + f4 * 4);
                xsf[(f4 * 4 + 0) * 132 + r] = v.x;
                xsf[(f4 * 4 + 1) * 132 + r] = v.y;
                xsf[(f4 * 4 + 2) * 132 + r] = v.z;
                xsf[(f4 * 4 + 3) * 132 + r] = v.w;
            }
        }
        {
            const int f4 = tid & 3;
            const int hh = tid >> 2;
#pragma unroll
            for (int q2 = 0; q2 < 2; ++q2) {
                const int kl = f4 * 4 + 16 * q2;
                const float4 v = *(const float4*)(w1 + (size_t)hh * IN_F + k0 + kl);
                wsf[(kl + 0) * 68 + hh] = v.x;
                wsf[(kl + 1) * 68 + hh] = v.y;
                wsf[(kl + 2) * 68 + hh] = v.z;
                wsf[(kl + 3) * 68 + hh] = v.w;
            }
        }
        __syncthreads();
#pragma unroll 4
        for (int k = 0; k < 32; ++k) {
            const float4 wv = *(const float4*)&wsf[k * 68 + hq * 4];
            const float4 xa = *(const float4*)&xsf[k * 132 + nq * 8];
            const float4 xb = *(const float4*)&xsf[k * 132 + nq * 8 + 4];
            const float xv[8] = {xa.x, xa.y, xa.z, xa.w, xb.x, xb.y, xb.z, xb.w};
            const float wvv[4] = {wv.x, wv.y, wv.z, wv.w};
#pragma unroll
            for (int j = 0; j < 8; ++j)
#pragma unroll
                for (int i = 0; i < 4; ++i) acc[j][i] += xv[j] * wvv[i];
        }
    }
#pragma unroll
    for (int j = 0; j < 8; ++j) {
        const int row = n0 + nq * 8 + j;
        if (row < N) {
            float4 o;
            o.x = tanhf(acc[j][0]); o.y = tanhf(acc[j][1]);
            o.z = tanhf(acc[j][2]); o.w = tanhf(acc[j][3]);
            *(float4*)(h + (size_t)row * NH + hq * 4) = o;
        }
    }
}

// ---------------- MLP kernel 2: local = h @ w2.T ----------------
__global__ __launch_bounds__(256) void k_mlp2(const float* __restrict__ h,
                                              const float* __restrict__ w2,
                                              float* __restrict__ local, int N) {
    __shared__ float w2s[32 * 68];
    const int tid = threadIdx.x;
    {
        const int c = tid >> 3, f4 = tid & 7;
        *(float4*)&w2s[c * 68 + f4 * 4]       = *(const float4*)(w2 + c * NH + f4 * 4);
        *(float4*)&w2s[c * 68 + (f4 + 8) * 4] = *(const float4*)(w2 + c * NH + (f4 + 8) * 4);
    }
    __syncthreads();
    const int c = tid & 31, nl = tid >> 5;
    const int n = blockIdx.x * 8 + nl;
    if (n >= N) return;
    float acc = 0.f;
#pragma unroll
    for (int h4 = 0; h4 < NH / 4; ++h4) {
        const float4 hv = *(const float4*)(h + (size_t)n * NH + h4 * 4);
        const float4 wv = *(const float4*)&w2s[c * 68 + h4 * 4];
        acc += hv.x * wv.x + hv.y * wv.y + hv.z * wv.z + hv.w * wv.w;
    }
    local[(size_t)n * NC + c] = acc;
}

// ---------------- bucket-level CSR build ----------------
__global__ __launch_bounds__(256) void k_zero(int* __restrict__ a, int n) {
    const int i = blockIdx.x * 256 + threadIdx.x;
    if (i < n) a[i] = 0;
}

// per-bucket histogram with LDS pre-aggregation; CHUNK=16384 edges per block
__global__ __launch_bounds__(256) void k_bhist(const int* __restrict__ rows,
                                               int* __restrict__ bcnt, int E, int NBK) {
    __shared__ int s[MAXBK];
    const int tid = threadIdx.x;
    for (int i = tid; i < NBK; i += 256) s[i] = 0;
    __syncthreads();
    const int base = blockIdx.x * 16384;
#pragma unroll 4
    for (int i = tid; i < 16384; i += 256) {
        const int e = base + i;
        if (e < E) atomicAdd(&s[rows[e] >> 6], 1);
    }
    __syncthreads();
    for (int i = tid; i < NBK; i += 256) {
        const int v = s[i];
        if (v) atomicAdd(&bcnt[i], v);
    }
}

// single block: exclusive scan of bcnt -> bstart (+ total at [NBK]) and bcur
__global__ __launch_bounds__(256) void k_bscan(const int* __restrict__ bcnt,
                                               int* __restrict__ bstart,
                                               int* __restrict__ bcur, int NBK) {
    __shared__ int part[256];
    const int t = threadIdx.x;
    int v[8]; int sum = 0;
#pragma unroll
    for (int i = 0; i < 8; ++i) {
        const int idx = t * 8 + i;
        v[i] = (idx < NBK) ? bcnt[idx] : 0;
        sum += v[i];
    }
    part[t] = sum;
    __syncthreads();
    for (int off = 1; off < 256; off <<= 1) {
        const int add = (t >= off) ? part[t - off] : 0;
        __syncthreads();
        part[t] += add;
        __syncthreads();
    }
    int run = (t == 0) ? 0 : part[t - 1];
#pragma unroll
    for (int i = 0; i < 8; ++i) {
        const int idx = t * 8 + i;
        if (idx < NBK) { bstart[idx] = run; bcur[idx] = run; run += v[i]; }
    }
    if (t == 255) bstart[NBK] = part[255];
}

// pass A: scatter packed (rowlocal<<17 | col) into bucket regions
__global__ __launch_bounds__(256) void k_bucket(const int* __restrict__ rows,
                                                const int* __restrict__ cols,
                                                int* __restrict__ bcur,
                                                int* __restrict__ bb, int E) {
    const int e = blockIdx.x * 256 + threadIdx.x;
    if (e < E) {
        const int r = rows[e];
        const int pos = atomicAdd(&bcur[r >> 6], 1);
        bb[pos] = cols[e] | ((r & 63) << COLBITS);
    }
}

// pass B: one block per bucket -> final CSR cols + rp + rsq
__global__ __launch_bounds__(256) void k_csr(const int* __restrict__ bstart,
                                             const int* __restrict__ bb,
                                             int* __restrict__ cs,
                                             int* __restrict__ rp,
                                             float* __restrict__ rsq, int N, int E) {
    __shared__ int cnt[BROWS];
    __shared__ int cur[BROWS];
    const int b = blockIdx.x;
    const int tid = threadIdx.x;
    const int base = bstart[b], end = bstart[b + 1];
    if (tid < BROWS) cnt[tid] = 0;
    __syncthreads();
    for (int e = base + tid; e < end; e += 256)
        atomicAdd(&cnt[(bb[e] >> COLBITS) & 63], 1);
    __syncthreads();
    if (tid < 64) {   // wave 0: inclusive shfl-scan over 64 lanes
        const int v = cnt[tid];
        int x = v;
#pragma unroll
        for (int off = 1; off < 64; off <<= 1) {
            const int up = __shfl_up(x, off);
            if (tid >= off) x += up;
        }
        const int excl = base + x - v;
        cur[tid] = excl;
        const int row = b * BROWS + tid;
        if (row < N) {
            rp[row]  = excl;
            rsq[row] = rsqrtf((float)v);   // deg >= 1 (self loops)
        }
    }
    if (b == 0 && tid == 0) rp[N] = E;
    __syncthreads();
    for (int e = base + tid; e < end; e += 256) {
        const int w = bb[e];
        const int pos = atomicAdd(&cur[(w >> COLBITS) & 63], 1);
        cs[pos] = w & ((1 << COLBITS) - 1);
    }
}

// u0 = rsq (.) local
__global__ __launch_bounds__(256) void k_scale(const float* __restrict__ local,
                                               const float* __restrict__ rsq,
                                               float* __restrict__ u, int N) {
    const int i4 = blockIdx.x * 256 + threadIdx.x;   // float4 index, NC/4 = 8 per row
    if (i4 < N * 8) {
        const float s = rsq[i4 >> 3];
        float4 v = ((const float4*)local)[i4];
        v.x *= s; v.y *= s; v.z *= s; v.w *= s;
        ((float4*)u)[i4] = v;
    }
}

// ---------------- SpMM on u: S = sum_e u[col][:];  p' = 0.9*rsq[r]*S + 0.1*local
// out = final ? p' : rsq[r]*p'
__global__ __launch_bounds__(256) void k_spmm(const int* __restrict__ rp,
                                              const int* __restrict__ cs,
                                              const float* __restrict__ u,
                                              const float* __restrict__ local,
                                              const float* __restrict__ rsq,
                                              float* __restrict__ out, int N, int final_it) {
    const int row = blockIdx.x * 8 + (threadIdx.x >> 5);
    if (row >= N) return;
    const int lane = threadIdx.x & 31;
    const int g = lane >> 3;     // 0..3 edge slot
    const int q = lane & 7;      // 0..7 class quad
    const int e0 = rp[row], e1 = rp[row + 1];

    float4 accA = {0.f, 0.f, 0.f, 0.f};
    float4 accB = {0.f, 0.f, 0.f, 0.f};
    const int nIter = (e1 - e0 + 7) >> 3;
    for (int it = 0; it < nIter; ++it) {
        const int eA = e0 + it * 8 + g;
        const int eB = eA + 4;
        const int cA = cs[(eA < e1) ? eA : (e1 - 1)];
        const int cB = cs[(eB < e1) ? eB : (e1 - 1)];
        const float4 pA = *(const float4*)(u + (size_t)cA * NC + q * 4);
        const float4 pB = *(const float4*)(u + (size_t)cB * NC + q * 4);
        const float mA = (eA < e1) ? 1.f : 0.f;
        const float mB = (eB < e1) ? 1.f : 0.f;
        accA.x += mA * pA.x; accA.y += mA * pA.y; accA.z += mA * pA.z; accA.w += mA * pA.w;
        accB.x += mB * pB.x; accB.y += mB * pB.y; accB.z += mB * pB.z; accB.w += mB * pB.w;
    }
    float4 acc;
    acc.x = accA.x + accB.x; acc.y = accA.y + accB.y;
    acc.z = accA.z + accB.z; acc.w = accA.w + accB.w;
#pragma unroll
    for (int mask = 8; mask <= 16; mask <<= 1) {
        acc.x += __shfl_xor(acc.x, mask);
        acc.y += __shfl_xor(acc.y, mask);
        acc.z += __shfl_xor(acc.z, mask);
        acc.w += __shfl_xor(acc.w, mask);
    }
    if (g == 0) {
        const float s  = rsq[row];
        const float k0 = (1.0f - PPR_ALPHA) * s;
        const float4 lv = *(const float4*)(local + (size_t)row * NC + q * 4);
        float4 o;
        o.x = k0 * acc.x + PPR_ALPHA * lv.x;
        o.y = k0 * acc.y + PPR_ALPHA * lv.y;
        o.z = k0 * acc.z + PPR_ALPHA * lv.z;
        o.w = k0 * acc.w + PPR_ALPHA * lv.w;
        if (!final_it) { o.x *= s; o.y *= s; o.z *= s; o.w *= s; }
        *(float4*)(out + (size_t)row * NC + q * 4) = o;
    }
}

extern "C" void kernel_launch(void* const* d_in, const int* in_sizes, int n_in,
                              void* d_out, int out_size, void* d_ws, size_t ws_size,
                              hipStream_t stream) {
    const float* x    = (const float*)d_in[0];
    const float* w1   = (const float*)d_in[1];
    const float* w2   = (const float*)d_in[2];
    const int*   rows = (const int*)d_in[3];
    const int*   cols = (const int*)d_in[4];
    // vals (d_in[5]) no longer needed: recomputed from degrees

    const int N = in_sizes[0] / IN_F;   // 100000
    const int E = in_sizes[3];          // 3300000
    const int NBK = (N + BROWS - 1) / BROWS;   // 1563, <= MAXBK

    auto align16 = [](size_t v) { return (v + 15) & ~(size_t)15; };
    char* ws = (char*)d_ws;
    const size_t szH  = align16((size_t)N * NH * 4);   // h (25.6 MB)
    const size_t szBB = align16((size_t)E * 4);        // packed bucket buf (13.2 MB)
    const size_t szA  = (szH > szBB) ? szH : szBB;

    float* hbuf = (float*)(ws + 0);     // region A: h first, then bucket buffer
    int*   bb   = (int*)(ws + 0);
    size_t off = szA;
    int*   cs     = (int*)(ws + off);   off += align16((size_t)E * 4);
    float* localb = (float*)(ws + off); off += align16((size_t)N * NC * 4);
    float* ubufA  = (float*)(ws + off); off += align16((size_t)N * NC * 4);
    int*   rp     = (int*)(ws + off);   off += align16((size_t)(N + 1) * 4);
    float* rsq    = (float*)(ws + off); off += align16((size_t)N * 4);
    int*   bcnt   = (int*)(ws + off);   off += align16((size_t)NBK * 4);
    int*   bstart = (int*)(ws + off);   off += align16((size_t)(NBK + 1) * 4);
    int*   bcur   = (int*)(ws + off);   off += align16((size_t)NBK * 4);
    (void)ws_size; (void)n_in; (void)out_size;

    // MLP (h lives in region A; must finish before pass A overwrites it)
    k_mlp1<<<(N + 127) / 128, 256, 0, stream>>>(x, w1, hbuf, N);
    k_mlp2<<<(N + 7) / 8, 256, 0, stream>>>(hbuf, w2, localb, N);

    // bucketed CSR build
    k_zero<<<(NBK + 255) / 256, 256, 0, stream>>>(bcnt, NBK);
    k_bhist<<<(E + 16383) / 16384, 256, 0, stream>>>(rows, bcnt, E, NBK);
    k_bscan<<<1, 256, 0, stream>>>(bcnt, bstart, bcur, NBK);
    k_bucket<<<(E + 255) / 256, 256, 0, stream>>>(rows, cols, bcur, bb, E);
    k_csr<<<NBK, 256, 0, stream>>>(bstart, bb, cs, rp, rsq, N, E);

    // u0 = rsq (.) local  -> buffer B (= d_out; overwritten each iteration pair)
    float* A = ubufA;
    float* B = (float*)d_out;
    k_scale<<<(N * 8 + 255) / 256, 256, 0, stream>>>(localb, rsq, B, N);

    // 10 iterations: odd it: B->A, even it: A->B; it 10 (even) lands in d_out
    const int spmm_grid = (N + 7) / 8;
    for (int it = 1; it <= NITER; ++it) {
        const float* src = (it & 1) ? B : A;
        float*       dst = (it & 1) ? A : B;
        k_spmm<<<spmm_grid, 256, 0, stream>>>(rp, cs, src, localb, rsq, dst, N,
                                              (it == NITER) ? 1 : 0);
    }
}

// Round 5
// 1310.356 us; speedup vs baseline: 1.1183x; 1.1183x over previous
//
#include <hip/hip_runtime.h>
#include <math.h>

#define IN_F 512
#define NH   64
#define NC   32
#define PPR_ALPHA 0.1f
#define NITER 10

// ---------------- MLP kernel 1: h = tanh(x @ w1.T), h is [N][64] ----------------
__global__ __launch_bounds__(256) void k_mlp1(const float* __restrict__ x,
                                              const float* __restrict__ w1,
                                              float* __restrict__ h, int N) {
    __shared__ float xsf[32 * 132];
    __shared__ float wsf[32 * 68];

    const int tid = threadIdx.x;
    const int n0  = blockIdx.x * 128;
    const int hq  = tid & 15;
    const int nq  = tid >> 4;

    float acc[8][4];
#pragma unroll
    for (int j = 0; j < 8; ++j)
#pragma unroll
        for (int i = 0; i < 4; ++i) acc[j][i] = 0.f;

    for (int kt = 0; kt < IN_F / 32; ++kt) {
        const int k0 = kt * 32;
        __syncthreads();
        {
            const int f4 = tid & 7;
            const int r0 = tid >> 3;
#pragma unroll
            for (int q2 = 0; q2 < 4; ++q2) {
                const int r = r0 + 32 * q2;
                int row = n0 + r; if (row >= N) row = N - 1;
                const float4 v = *(const float4*)(x + (size_t)row * IN_F + k0 + f4 * 4);
                xsf[(f4 * 4 + 0) * 132 + r] = v.x;
                xsf[(f4 * 4 + 1) * 132 + r] = v.y;
                xsf[(f4 * 4 + 2) * 132 + r] = v.z;
                xsf[(f4 * 4 + 3) * 132 + r] = v.w;
            }
        }
        {
            const int f4 = tid & 3;
            const int hh = tid >> 2;
#pragma unroll
            for (int q2 = 0; q2 < 2; ++q2) {
                const int kl = f4 * 4 + 16 * q2;
                const float4 v = *(const float4*)(w1 + (size_t)hh * IN_F + k0 + kl);
                wsf[(kl + 0) * 68 + hh] = v.x;
                wsf[(kl + 1) * 68 + hh] = v.y;
                wsf[(kl + 2) * 68 + hh] = v.z;
                wsf[(kl + 3) * 68 + hh] = v.w;
            }
        }
        __syncthreads();
#pragma unroll 4
        for (int k = 0; k < 32; ++k) {
            const float4 wv = *(const float4*)&wsf[k * 68 + hq * 4];
            const float4 xa = *(const float4*)&xsf[k * 132 + nq * 8];
            const float4 xb = *(const float4*)&xsf[k * 132 + nq * 8 + 4];
            const float xv[8] = {xa.x, xa.y, xa.z, xa.w, xb.x, xb.y, xb.z, xb.w};
            const float wvv[4] = {wv.x, wv.y, wv.z, wv.w};
#pragma unroll
            for (int j = 0; j < 8; ++j)
#pragma unroll
                for (int i = 0; i < 4; ++i) acc[j][i] += xv[j] * wvv[i];
        }
    }
#pragma unroll
    for (int j = 0; j < 8; ++j) {
        const int row = n0 + nq * 8 + j;
        if (row < N) {
            float4 o;
            o.x = tanhf(acc[j][0]); o.y = tanhf(acc[j][1]);
            o.z = tanhf(acc[j][2]); o.w = tanhf(acc[j][3]);
            *(float4*)(h + (size_t)row * NH + hq * 4) = o;
        }
    }
}

// ---------------- MLP kernel 2: local = h @ w2.T ----------------
__global__ __launch_bounds__(256) void k_mlp2(const float* __restrict__ h,
                                              const float* __restrict__ w2,
                                              float* __restrict__ local, int N) {
    __shared__ float w2s[32 * 68];
    const int tid = threadIdx.x;
    {
        const int c = tid >> 3, f4 = tid & 7;
        *(float4*)&w2s[c * 68 + f4 * 4]       = *(const float4*)(w2 + c * NH + f4 * 4);
        *(float4*)&w2s[c * 68 + (f4 + 8) * 4] = *(const float4*)(w2 + c * NH + (f4 + 8) * 4);
    }
    __syncthreads();
    const int c = tid & 31, nl = tid >> 5;
    const int n = blockIdx.x * 8 + nl;
    if (n >= N) return;
    float acc = 0.f;
#pragma unroll
    for (int h4 = 0; h4 < NH / 4; ++h4) {
        const float4 hv = *(const float4*)(h + (size_t)n * NH + h4 * 4);
        const float4 wv = *(const float4*)&w2s[c * 68 + h4 * 4];
        acc += hv.x * wv.x + hv.y * wv.y + hv.z * wv.z + hv.w * wv.w;
    }
    local[(size_t)n * NC + c] = acc;
}

// ---------------- CSR build (direct scatter, padded rows) ----------------
__global__ __launch_bounds__(256) void k_zero(int* __restrict__ a, int n) {
    const int i = blockIdx.x * 256 + threadIdx.x;
    if (i < n) a[i] = 0;
}
__global__ __launch_bounds__(256) void k_hist(const int* __restrict__ rows,
                                              int* __restrict__ counts, int E) {
    const int e = blockIdx.x * 256 + threadIdx.x;
    if (e < E) atomicAdd(&counts[rows[e]], 1);
}
// block sums of PADDED counts (pad each row's count up to multiple of 8)
__global__ __launch_bounds__(256) void k_blocksum(const int* __restrict__ counts,
                                                  int* __restrict__ bsum, int N) {
    __shared__ int s[256];
    const int i = blockIdx.x * 256 + threadIdx.x;
    const int v = (i < N) ? counts[i] : 0;
    s[threadIdx.x] = (v + 7) & ~7;
    __syncthreads();
    for (int off = 128; off > 0; off >>= 1) {
        if (threadIdx.x < off) s[threadIdx.x] += s[threadIdx.x + off];
        __syncthreads();
    }
    if (threadIdx.x == 0) bsum[blockIdx.x] = s[0];
}
__global__ __launch_bounds__(512) void k_scanb(int* __restrict__ bsum, int NB) {
    __shared__ int s[512];
    const int t = threadIdx.x;
    const int v = (t < NB) ? bsum[t] : 0;
    s[t] = v;
    __syncthreads();
    for (int off = 1; off < 512; off <<= 1) {
        const int add = (t >= off) ? s[t - off] : 0;
        __syncthreads();
        s[t] += add;
        __syncthreads();
    }
    if (t < NB) bsum[t] = s[t] - v;
}
// scan of padded counts -> rp, cursor; also rsq from true counts
__global__ __launch_bounds__(256) void k_scan3(const int* __restrict__ counts,
                                               const int* __restrict__ bsum,
                                               int* __restrict__ rp,
                                               int* __restrict__ cursor,
                                               float* __restrict__ rsq, int N) {
    __shared__ int s[256];
    const int t = threadIdx.x;
    const int i = blockIdx.x * 256 + t;
    const int v  = (i < N) ? counts[i] : 0;
    const int pv = (v + 7) & ~7;
    s[t] = pv;
    __syncthreads();
    for (int off = 1; off < 256; off <<= 1) {
        const int add = (t >= off) ? s[t - off] : 0;
        __syncthreads();
        s[t] += add;
        __syncthreads();
    }
    if (i < N) {
        const int ex = s[t] - pv + bsum[blockIdx.x];
        rp[i] = ex;
        cursor[i] = ex;
        rsq[i] = rsqrtf((float)v);   // deg >= 1 (self loops)
    }
}
// scatter col (4 B payload) into padded CSR slots
__global__ __launch_bounds__(256) void k_scatter(const int* __restrict__ rows,
                                                 const int* __restrict__ cols,
                                                 int* __restrict__ cursor,
                                                 int* __restrict__ cs, int E) {
    const int e = blockIdx.x * 256 + threadIdx.x;
    if (e < E) {
        const int pos = atomicAdd(&cursor[rows[e]], 1);
        cs[pos] = cols[e];
    }
}
// fill pad slots with sentinel col = N (u[N] == 0)
__global__ __launch_bounds__(256) void k_fill(const int* __restrict__ counts,
                                              const int* __restrict__ rp,
                                              int* __restrict__ cs, int N) {
    const int i = blockIdx.x * 256 + threadIdx.x;
    if (i < N) {
        const int cnt = counts[i];
        const int pcnt = (cnt + 7) & ~7;
        const int base = rp[i];
        for (int j = cnt; j < pcnt; ++j) cs[base + j] = N;
    }
}
// zero sentinel row N of both u buffers
__global__ __launch_bounds__(64) void k_zrow(float* __restrict__ a,
                                             float* __restrict__ b, int N) {
    const int t = threadIdx.x;
    if (t < NC) a[(size_t)N * NC + t] = 0.f;
    else        b[(size_t)N * NC + (t - NC)] = 0.f;
}
// u0 = rsq (.) local
__global__ __launch_bounds__(256) void k_scale(const float* __restrict__ local,
                                               const float* __restrict__ rsq,
                                               float* __restrict__ u, int N) {
    const int i4 = blockIdx.x * 256 + threadIdx.x;
    if (i4 < N * 8) {
        const float s = rsq[i4 >> 3];
        float4 v = ((const float4*)local)[i4];
        v.x *= s; v.y *= s; v.z *= s; v.w *= s;
        ((float4*)u)[i4] = v;
    }
}

// ---------------- SpMM on u: S = sum_e u[col][:];  p' = 0.9*rsq[r]*S + 0.1*local
// out = final ? p' : rsq[r]*p'.  Rows padded to x8 -> branch-free inner loop.
__global__ __launch_bounds__(256) void k_spmm(const int* __restrict__ rp,
                                              const int* __restrict__ cs,
                                              const float* __restrict__ u,
                                              const float* __restrict__ local,
                                              const float* __restrict__ rsq,
                                              float* __restrict__ out, int N, int final_it) {
    const int row = blockIdx.x * 8 + (threadIdx.x >> 5);
    if (row >= N) return;
    const int lane = threadIdx.x & 31;
    const int g = lane >> 3;     // 0..3 edge slot
    const int q = lane & 7;      // 0..7 class quad
    const int e0 = rp[row], e1 = rp[row + 1];   // e1-e0 multiple of 8

    float4 accA = {0.f, 0.f, 0.f, 0.f};
    float4 accB = {0.f, 0.f, 0.f, 0.f};
    const int qoff = q * 4;
    for (int e = e0 + g; e < e1; e += 8) {
        const int cA = cs[e];
        const int cB = cs[e + 4];
        const float4 pA = *(const float4*)(u + cA * NC + qoff);
        const float4 pB = *(const float4*)(u + cB * NC + qoff);
        accA.x += pA.x; accA.y += pA.y; accA.z += pA.z; accA.w += pA.w;
        accB.x += pB.x; accB.y += pB.y; accB.z += pB.z; accB.w += pB.w;
    }
    float4 acc;
    acc.x = accA.x + accB.x; acc.y = accA.y + accB.y;
    acc.z = accA.z + accB.z; acc.w = accA.w + accB.w;
#pragma unroll
    for (int mask = 8; mask <= 16; mask <<= 1) {
        acc.x += __shfl_xor(acc.x, mask);
        acc.y += __shfl_xor(acc.y, mask);
        acc.z += __shfl_xor(acc.z, mask);
        acc.w += __shfl_xor(acc.w, mask);
    }
    if (g == 0) {
        const float s  = rsq[row];
        const float k0 = (1.0f - PPR_ALPHA) * s;
        const float4 lv = *(const float4*)(local + (size_t)row * NC + qoff);
        float4 o;
        o.x = k0 * acc.x + PPR_ALPHA * lv.x;
        o.y = k0 * acc.y + PPR_ALPHA * lv.y;
        o.z = k0 * acc.z + PPR_ALPHA * lv.z;
        o.w = k0 * acc.w + PPR_ALPHA * lv.w;
        if (!final_it) { o.x *= s; o.y *= s; o.z *= s; o.w *= s; }
        *(float4*)(out + (size_t)row * NC + qoff) = o;
    }
}

extern "C" void kernel_launch(void* const* d_in, const int* in_sizes, int n_in,
                              void* d_out, int out_size, void* d_ws, size_t ws_size,
                              hipStream_t stream) {
    const float* x    = (const float*)d_in[0];
    const float* w1   = (const float*)d_in[1];
    const float* w2   = (const float*)d_in[2];
    const int*   rows = (const int*)d_in[3];
    const int*   cols = (const int*)d_in[4];
    // vals (d_in[5]) recomputed from degrees

    const int N = in_sizes[0] / IN_F;   // 100000
    const int E = in_sizes[3];          // 3300000

    auto align16 = [](size_t v) { return (v + 15) & ~(size_t)15; };
    char* ws = (char*)d_ws;
    const size_t szH  = align16((size_t)N * NH * 4);          // h: 25.6 MB
    const size_t szCs = align16(((size_t)E + 8 * (size_t)N) * 4);  // padded cs: <= 16.4 MB
    const size_t szA  = (szH > szCs) ? szH : szCs;

    float* hbuf = (float*)(ws + 0);     // region A: h first, then padded cs
    int*   cs   = (int*)(ws + 0);
    size_t off = szA;
    float* localb = (float*)(ws + off); off += align16((size_t)N * NC * 4);
    float* uA     = (float*)(ws + off); off += align16((size_t)(N + 1) * NC * 4);
    float* uB     = (float*)(ws + off); off += align16((size_t)(N + 1) * NC * 4);
    int*   counts = (int*)(ws + off);   off += align16((size_t)N * 4);
    int*   rp     = (int*)(ws + off);   off += align16((size_t)(N + 1) * 4);
    int*   cursor = (int*)(ws + off);   off += align16((size_t)N * 4);
    float* rsq    = (float*)(ws + off); off += align16((size_t)N * 4);
    int*   bsum   = (int*)(ws + off);   off += align16((size_t)512 * 4);
    (void)ws_size; (void)n_in; (void)out_size;

    const int NB = (N + 255) / 256;     // 391 <= 512

    // MLP (h lives in region A; done before scatter overwrites it)
    k_mlp1<<<(N + 127) / 128, 256, 0, stream>>>(x, w1, hbuf, N);
    k_mlp2<<<(N + 7) / 8, 256, 0, stream>>>(hbuf, w2, localb, N);

    // CSR build with per-row padding to x8
    k_zero<<<NB, 256, 0, stream>>>(counts, N);
    k_hist<<<(E + 255) / 256, 256, 0, stream>>>(rows, counts, E);
    k_blocksum<<<NB, 256, 0, stream>>>(counts, bsum, N);
    k_scanb<<<1, 512, 0, stream>>>(bsum, NB);
    k_scan3<<<NB, 256, 0, stream>>>(counts, bsum, rp, cursor, rsq, N);
    // rp[N] = total padded edges (computed on the fly by last block in scan3 is racy;
    // instead set from padded total via a tiny kernel-free trick: k_fill reads rp[i] only,
    // and k_spmm needs rp[row+1] -> write it here)
    k_scatter<<<(E + 255) / 256, 256, 0, stream>>>(rows, cols, cursor, cs, E);
    k_fill<<<NB, 256, 0, stream>>>(counts, rp, cs, N);
    // rp[N]: after k_fill, cursor[N-1] is stale; compute rp[N] = rp[N-1] + pcnt[N-1]
    // via a 1-thread kernel
    {
        struct Last {
            static __global__ void set(const int* counts, int* rp, int N) {
                rp[N] = rp[N - 1] + ((counts[N - 1] + 7) & ~7);
            }
        };
        hipLaunchKernelGGL(Last::set, dim3(1), dim3(1), 0, stream, counts, rp, N);
    }

    k_zrow<<<1, 64, 0, stream>>>(uA, uB, N);
    k_scale<<<(N * 8 + 255) / 256, 256, 0, stream>>>(localb, rsq, uA, N);

    // its 1..9 ping-pong uA/uB (u-space); it 10 writes p to d_out
    float* outp = (float*)d_out;
    const int spmm_grid = (N + 7) / 8;
    for (int it = 1; it <= NITER; ++it) {
        const float* src = (it & 1) ? uA : uB;
        float*       dst = (it == NITER) ? outp : ((it & 1) ? uB : uA);
        k_spmm<<<spmm_grid, 256, 0, stream>>>(rp, cs, src, localb, rsq, dst, N,
                                              (it == NITER) ? 1 : 0);
    }
}